// Round 19
// baseline (556.200 us; speedup 1.0000x reference)
//
#include <hip/hip_runtime.h>
#include <hip/hip_fp16.h>
#include <float.h>

#define M_ROWS 32768
#define E_DIM  512
#define N_E    8192

#define BMR 64                  // rows per block (2 row-groups x 32)
#define NQ 4                    // quarters of the e-range
#define EQ (N_E / NQ)           // 2048 codes per quarter

typedef __attribute__((ext_vector_type(8))) _Float16 half8;
typedef __attribute__((ext_vector_type(4))) float f32x4;

__device__ __forceinline__ void gl_lds16(const void* g, void* l) {
    __builtin_amdgcn_global_load_lds(
        (const __attribute__((address_space(1))) unsigned int*)g,
        (__attribute__((address_space(3))) unsigned int*)l, 16, 0, 0);
}

#define MFMA16(A_, B_, C_) __builtin_amdgcn_mfma_f32_16x16x32_f16((A_), (B_), (C_), 0, 0, 0)

// ---------------- fp32 -> fp16 (RTNE) for Z ----------------
__global__ __launch_bounds__(256) void f16_cast_kernel(const float* __restrict__ X,
                                                       ushort* __restrict__ H,
                                                       int n4) {
    int i = blockIdx.x * 256 + threadIdx.x;
    if (i >= n4) return;
    float4 v = ((const float4*)X)[i];
    float c[4] = {v.x, v.y, v.z, v.w};
    ushort hh[4];
    #pragma unroll
    for (int j = 0; j < 4; j++) {
        __half hb = __float2half(c[j]);
        hh[j] = *(ushort*)&hb;
    }
    ushort4 h = {hh[0], hh[1], hh[2], hh[3]};
    ((ushort4*)H)[i] = h;
}

// ---------------- pack W fp32 -> fp16 fragment-linear tiles (R15-proven) ----------------
// Tile (et, kt) = 1024 B; byte t*4 holds elems for lane=t>>2:
// col = lane&15, k = kt*32 + (lane>>4)*8 + (t&3)*2 (+1 in high half).
__global__ __launch_bounds__(256) void pack_w_kernel(const float* __restrict__ W,
                                                     unsigned int* __restrict__ Wt) {
    __shared__ float Ws[16 * E_DIM];
    const int et = blockIdx.x;           // 512 e-tiles of 16 codes
    const int t = threadIdx.x;
    const float4* src = (const float4*)(W + (size_t)et * 16 * E_DIM);
    #pragma unroll
    for (int i = 0; i < 8; i++)
        ((float4*)Ws)[i * 256 + t] = src[i * 256 + t];
    __syncthreads();
    const int lane = t >> 2;
    const int col = lane & 15;
    const int koff = (lane >> 4) * 8 + (t & 3) * 2;
    unsigned int* dst = Wt + (size_t)et * 16 * 256 + t;
    #pragma unroll
    for (int kt = 0; kt < 16; kt++) {
        float f0 = Ws[col * E_DIM + kt * 32 + koff];
        float f1 = Ws[col * E_DIM + kt * 32 + koff + 1];
        __half h0 = __float2half(f0), h1 = __float2half(f1);
        unsigned int u = (unsigned int)(*(ushort*)&h0) | ((unsigned int)(*(ushort*)&h1) << 16);
        dst[kt * 256] = u;
    }
}

// ---------------- wnorm[e] = sum_k W[e][k]^2 (fp32, exact) ----------------
__global__ __launch_bounds__(256) void wnorm_kernel(const float* __restrict__ W,
                                                    float* __restrict__ wnorm) {
    int wave_id = (int)((blockIdx.x * blockDim.x + threadIdx.x) >> 6);
    int lane = threadIdx.x & 63;
    if (wave_id >= N_E) return;
    const float* row = W + (size_t)wave_id * E_DIM;
    float4 v0 = *(const float4*)(row + lane * 4);
    float4 v1 = *(const float4*)(row + 256 + lane * 4);
    float s = v0.x*v0.x + v0.y*v0.y + v0.z*v0.z + v0.w*v0.w
            + v1.x*v1.x + v1.y*v1.y + v1.z*v1.z + v1.w*v1.w;
    #pragma unroll
    for (int off = 32; off; off >>= 1) s += __shfl_down(s, off);
    if (lane == 0) wnorm[wave_id] = s;
}

struct Top2 { float v0, v1; int i0, i1; };

__device__ inline Top2 merge2(Top2 A, Top2 B) {
    bool af = (A.v0 < B.v0) || (A.v0 == B.v0 && A.i0 < B.i0);
    float Wv1 = af ? A.v1 : B.v1; int Wi1 = af ? A.i1 : B.i1;
    float Lv0 = af ? B.v0 : A.v0; int Li0 = af ? B.i0 : A.i0;
    bool s2 = (Wv1 < Lv0) || (Wv1 == Lv0 && Wi1 < Li0);
    Top2 R;
    R.v0 = af ? A.v0 : B.v0; R.i0 = af ? A.i0 : B.i0;
    R.v1 = s2 ? Wv1 : Lv0;   R.i1 = s2 ? Wi1 : Li0;
    return R;
}

// ---------------- fp16 MFMA screen (K=512) + per-row top-2 per QUARTER ----------------
// Screen semantics identical to PASSING R4..R18. Change vs R18 (measured: issued
// global B bytes 8 GB = the binding ~64 B/cy L1 path; rg-pair loads are duplicate
// issues): RG-SPLIT LOADS + LDS EXCHANGE. rg0 stages k-tiles 0-3 of each half-
// step, rg1 stages 4-7 -> each B byte issued ONCE globally (8->4 GB), exchanged
// via the separate 128 B/cy LDS pipe. Packed Wt tiles are fragment-linear, so
// global_load_lds needs NO swizzle (uniform base + lane*16, rule-21 canonical)
// and ds_read_b128 at lane*16 is contiguous/bank-clean. 3-slot pipeline (4cg x
// 8KB per slot, 96 KB), phase = half-col-step (8 k-tiles), counted vmcnt(4),
// stage distance 2, one barrier/phase (R7-proven invariant). A path, fold,
// merge: R18-verbatim. Bbuf registers freed.
__global__ __launch_bounds__(512, 2) void argmin_mfma(
        const ushort* __restrict__ Zh, const char* __restrict__ Wt,
        const float* __restrict__ wnorm, int* __restrict__ cand) {
    __shared__ __align__(16) char Lds[98304];   // A prologue reuses [0,64K); 3 B slots of 32K

    const int t = threadIdx.x;
    const int lane = t & 63;
    const int wid = t >> 6;            // 0..7
    const int cg = wid & 3;            // col-group (16 cols)
    const int rg = wid >> 2;           // row-group (32 rows) + load-half
    const int l15 = lane & 15, l4 = lane >> 4;

    // chunked XCD remap (2048 blocks, 8 XCDs, 256-block chunks; bijective).
    const int id = blockIdx.x;
    const int orig = (id & 7) * 256 + (id >> 3);
    const int quarter = orig >> 9;     // 2 XCDs per quarter
    const int rowblk = orig & 511;
    const int row0 = rowblk * BMR;
    const int ebase = quarter * EQ;

    // ---- A prologue staging: 64 rows x 512 k, ks-major (R18-verbatim) ----
    const int arow = (t >> 2) & 63;
    const int aswz = (t & 3) ^ ((arow >> 1) & 3);
    const ushort* Ag = Zh + (size_t)(row0 + arow) * E_DIM + ((t >> 8) & 1) * 32 + aswz * 8;
    #pragma unroll
    for (int j = 0; j < 8; j++)
        gl_lds16(Ag + j * 64, Lds + j * 8192 + t * 16);

    asm volatile("s_waitcnt vmcnt(0)" ::: "memory");
    __builtin_amdgcn_s_barrier();
    __builtin_amdgcn_sched_barrier(0);

    // ---- A fragments -> registers (wave's own 32 rows; R18-verbatim) ----
    const int kchunk_b = (l4 ^ ((l15 >> 1) & 3)) * 16;
    half8 Areg[32];                    // [ks*2 + mi]
    #pragma unroll
    for (int ks = 0; ks < 16; ks++)
        #pragma unroll
        for (int mi = 0; mi < 2; mi++)
            Areg[ks * 2 + mi] = *(const half8*)(Lds + ks * 4096
                                + (rg * 32 + mi * 16 + l15) * 64 + kchunk_b);
    asm volatile("s_waitcnt lgkmcnt(0)" ::: "memory");
    __builtin_amdgcn_sched_barrier(0);
    __builtin_amdgcn_s_barrier();      // all waves done reading A before B slots overwrite
    __builtin_amdgcn_sched_barrier(0);

    // ---- B: packed tiles. Phase (s, h): 8 k-tiles; rg stages its half (4 x 1KB).
    // Global src per-lane (lane*16); LDS dst uniform base (+ lane*16 by HW).
    const char* BpS = Wt + ((size_t)(ebase >> 4) + cg) * 16384 + rg * 4096 + lane * 16;
    const char* const ldsRd = Lds + cg * 8192 + lane * 16;   // + slot*32768 + f*1024

    int colb = ebase + cg * 16 + l15;
    const float* wnp = wnorm + colb;
    float wn_cur = 0.0f;

    // per-thread top2 over 8 row-slots q=mi*4+r; row = rg*32 + mi*16 + l4*4 + r
    float v0[8], v1[8];
    int i0[8], i1[8];
    #pragma unroll
    for (int q = 0; q < 8; q++) { v0[q] = FLT_MAX; v1[q] = FLT_MAX; i0[q] = 0; i1[q] = 0; }

    f32x4 acc[2];
    acc[0] = (f32x4){0.f, 0.f, 0.f, 0.f};
    acc[1] = (f32x4){0.f, 0.f, 0.f, 0.f};

    #define STG(SSLOT, SSREL, SH) do {                                           \
        const char* _s = BpS + (SSREL) * 65536 + (SH) * 8192;                    \
        char* _d = Lds + (SSLOT) * 32768 + cg * 8192 + rg * 4096;                \
        gl_lds16(_s,        _d);                                                 \
        gl_lds16(_s + 1024, _d + 1024);                                          \
        gl_lds16(_s + 2048, _d + 2048);                                          \
        gl_lds16(_s + 3072, _d + 3072);                                          \
    } while (0)

    // Invariant at each wait: everything older than the newest 4 vm-ops is
    // forced -> stage(p) complete for ALL waves after the barrier (wn preloads
    // only make the wait stricter, never looser).
    #define PHASE(RSLOT, H, VMSTR, DOSTG, SSLOT, SSREL, SH, DOWNLD, DOFOLD) do { \
        asm volatile("s_waitcnt " VMSTR ::: "memory");                           \
        __builtin_amdgcn_s_barrier();                                            \
        __builtin_amdgcn_sched_barrier(0);                                       \
        if (DOSTG) STG(SSLOT, SSREL, SH);                                        \
        if (DOWNLD) wn_cur = wnp[0];                                             \
        {                                                                        \
            const char* _b = ldsRd + (RSLOT) * 32768;                            \
            half8 _f[8];                                                         \
            _Pragma("unroll")                                                    \
            for (int f = 0; f < 8; f++) _f[f] = *(const half8*)(_b + f * 1024);  \
            __builtin_amdgcn_s_setprio(1);                                       \
            _Pragma("unroll")                                                    \
            for (int f = 0; f < 8; f++) {                                        \
                acc[0] = MFMA16(Areg[((H) * 8 + f) * 2 + 0], _f[f], acc[0]);     \
                acc[1] = MFMA16(Areg[((H) * 8 + f) * 2 + 1], _f[f], acc[1]);     \
            }                                                                    \
            __builtin_amdgcn_s_setprio(0);                                       \
        }                                                                        \
        if (DOFOLD) {                                                            \
            _Pragma("unroll")                                                    \
            for (int mi = 0; mi < 2; mi++)                                       \
                _Pragma("unroll")                                                \
                for (int r = 0; r < 4; r++) {                                    \
                    float sc = fmaf(-2.0f, acc[mi][r], wn_cur);                  \
                    int q = mi * 4 + r;                                          \
                    if (sc < v0[q])      { v1[q] = v0[q]; i1[q] = i0[q]; v0[q] = sc; i0[q] = colb; } \
                    else if (sc < v1[q]) { v1[q] = sc; i1[q] = colb; }           \
                }                                                                \
            acc[0] = (f32x4){0.f, 0.f, 0.f, 0.f};                                \
            acc[1] = (f32x4){0.f, 0.f, 0.f, 0.f};                                \
            colb += 64; wnp += 64;                                               \
        }                                                                        \
    } while (0)

    // prologue: stage phase 0 -> slot 0, phase 1 -> slot 1
    STG(0, 0, 0);
    STG(1, 0, 1);

    // 64 phases total: 10 x 6-phase body (s 0..29) + 4-phase tail (s 30,31)
    for (int k = 0; k < 10; ++k) {
        PHASE(0, 0, "vmcnt(4)", 1, 2, 1, 0, 1, 0);
        PHASE(1, 1, "vmcnt(4)", 1, 0, 1, 1, 0, 1);
        PHASE(2, 0, "vmcnt(4)", 1, 1, 2, 0, 1, 0);
        PHASE(0, 1, "vmcnt(4)", 1, 2, 2, 1, 0, 1);
        PHASE(1, 0, "vmcnt(4)", 1, 0, 3, 0, 1, 0);
        PHASE(2, 1, "vmcnt(4)", 1, 1, 3, 1, 0, 1);
        BpS += 3 * 65536;
    }
    PHASE(0, 0, "vmcnt(4)", 1, 2, 1, 0, 1, 0);   // p60 (s30,h0); stage (s31,h0)
    PHASE(1, 1, "vmcnt(4)", 1, 0, 1, 1, 0, 1);   // p61 (s30,h1); stage (s31,h1)
    PHASE(2, 0, "vmcnt(4)", 0, 0, 0, 0, 1, 0);   // p62 (s31,h0)
    PHASE(0, 1, "vmcnt(0)", 0, 0, 0, 0, 0, 1);   // p63 (s31,h1)
    #undef PHASE
    #undef STG

    // ---- merge: 16-lane butterfly, then cross-cg merge via LDS (R18-verbatim) ----
    __syncthreads();
    float4* SmTop = (float4*)Lds;       // [64 rows][4 col-groups]

    #pragma unroll
    for (int mi = 0; mi < 2; mi++)
        #pragma unroll
        for (int r = 0; r < 4; r++) {
            int q = mi * 4 + r;
            Top2 T = {v0[q], v1[q], i0[q], i1[q]};
            #pragma unroll
            for (int mk = 1; mk <= 8; mk <<= 1) {
                Top2 O;
                O.v0 = __shfl_xor(T.v0, mk); O.v1 = __shfl_xor(T.v1, mk);
                O.i0 = __shfl_xor(T.i0, mk); O.i1 = __shfl_xor(T.i1, mk);
                T = merge2(T, O);
            }
            if (l15 == 0) {
                int rl = rg * 32 + mi * 16 + l4 * 4 + r;
                SmTop[rl * 4 + cg] = make_float4(T.v0, __int_as_float(T.i0), T.v1, __int_as_float(T.i1));
            }
        }
    __syncthreads();
    if (t < BMR) {
        Top2 q[4];
        #pragma unroll
        for (int j = 0; j < 4; j++) {
            float4 F = SmTop[t * 4 + j];
            q[j].v0 = F.x; q[j].i0 = __float_as_int(F.y);
            q[j].v1 = F.z; q[j].i1 = __float_as_int(F.w);
        }
        Top2 T = merge2(merge2(q[0], q[1]), merge2(q[2], q[3]));
        cand[(size_t)(row0 + t) * (2 * NQ) + quarter * 2 + 0] = T.i0;
        cand[(size_t)(row0 + t) * (2 * NQ) + quarter * 2 + 1] = T.i1;
    }
}

// ---------------- fp32 rescore of 8 candidates + gather z_q + loss partial ----------------
__global__ __launch_bounds__(256) void rescore_gather_loss(
        const float* __restrict__ Z, const float* __restrict__ W,
        const float* __restrict__ wnorm, const int* __restrict__ cand,
        float* __restrict__ out, float* __restrict__ partials) {
    const int n = blockIdx.x;
    const int t = threadIdx.x;
    const int lane = t & 63, wv = t >> 6;
    int c[8];
    #pragma unroll
    for (int j = 0; j < 8; j++) c[j] = cand[(size_t)n * 8 + j];
    float2 zv = ((const float2*)(Z + (size_t)n * E_DIM))[t];
    float2 wvv[8];
    #pragma unroll
    for (int j = 0; j < 8; j++)
        wvv[j] = ((const float2*)(W + (size_t)c[j] * E_DIM))[t];
    __shared__ float red[4][8];
    #pragma unroll
    for (int j = 0; j < 8; j++) {
        float s = zv.x * wvv[j].x + zv.y * wvv[j].y;
        #pragma unroll
        for (int off = 32; off; off >>= 1) s += __shfl_down(s, off);
        if (lane == 0) red[wv][j] = s;
    }
    __syncthreads();
    float best = FLT_MAX; int bj = 0, bc = 0x7fffffff;
    #pragma unroll
    for (int j = 0; j < 8; j++) {
        float d = red[0][j] + red[1][j] + red[2][j] + red[3][j];
        float s = wnorm[c[j]] - 2.0f * d;
        if (s < best || (s == best && c[j] < bc)) { best = s; bj = j; bc = c[j]; }
    }
    float2 wq = wvv[0];                 // static-index select (rule #20)
    #pragma unroll
    for (int j = 1; j < 8; j++) if (bj == j) wq = wvv[j];
    ((float2*)(out + 1 + (size_t)n * E_DIM))[t] = wq;   // z_q_st == z_q numerically
    float d0 = wq.x - zv.x, d1 = wq.y - zv.y;
    float sl = d0 * d0 + d1 * d1;
    #pragma unroll
    for (int off = 32; off; off >>= 1) sl += __shfl_down(sl, off);
    __shared__ float red2[4];
    if (lane == 0) red2[wv] = sl;
    __syncthreads();
    if (t == 0) {
        partials[n] = red2[0] + red2[1] + red2[2] + red2[3];
        out[1 + (size_t)M_ROWS * E_DIM + n] = (float)bc;
    }
}

// ---------------- deterministic final loss reduction ----------------
__global__ __launch_bounds__(256) void loss_reduce_kernel(const float* __restrict__ partials,
                                                          float* __restrict__ out) {
    const int t = threadIdx.x;
    float s = 0.0f;
    for (int i = t; i < M_ROWS; i += 256) s += partials[i];
    #pragma unroll
    for (int off = 32; off; off >>= 1) s += __shfl_down(s, off);
    __shared__ float red[4];
    if ((t & 63) == 0) red[t >> 6] = s;
    __syncthreads();
    if (t == 0) {
        float total = red[0] + red[1] + red[2] + red[3];
        out[0] = 2.0f * total / ((float)M_ROWS * (float)E_DIM);  // beta=1 collapses
    }
}

extern "C" void kernel_launch(void* const* d_in, const int* in_sizes, int n_in,
                              void* d_out, int out_size, void* d_ws, size_t ws_size,
                              hipStream_t stream) {
    const float* Z = (const float*)d_in[0];
    const float* W = (const float*)d_in[1];
    float* out = (float*)d_out;

    char* p = (char*)d_ws;
    ushort* Zh = (ushort*)p;             p += (size_t)M_ROWS * E_DIM * 2;
    unsigned int* Wt = (unsigned int*)p; p += (size_t)N_E * E_DIM * 2;
    float* wnorm = (float*)p;            p += (size_t)N_E * 4;
    int* cand = (int*)p;                 p += (size_t)M_ROWS * 8 * 4;
    float* partials = (float*)p;         p += (size_t)M_ROWS * 4;

    f16_cast_kernel<<<(M_ROWS * E_DIM / 4 + 255) / 256, 256, 0, stream>>>(Z, Zh, M_ROWS * E_DIM / 4);
    pack_w_kernel<<<N_E / 16, 256, 0, stream>>>(W, Wt);
    wnorm_kernel<<<N_E / 4, 256, 0, stream>>>(W, wnorm);
    argmin_mfma<<<NQ * (M_ROWS / BMR), 512, 0, stream>>>(Zh, (const char*)Wt, wnorm, cand);
    rescore_gather_loss<<<M_ROWS, 256, 0, stream>>>(Z, W, wnorm, cand, out, partials);
    loss_reduce_kernel<<<1, 256, 0, stream>>>(partials, out);
}

// Round 20
// 541.532 us; speedup vs baseline: 1.0271x; 1.0271x over previous
//
#include <hip/hip_runtime.h>
#include <hip/hip_fp16.h>
#include <float.h>

#define M_ROWS 32768
#define E_DIM  512
#define N_E    8192

#define BMR 64                  // rows per block (2 row-groups x 32)
#define NQ 4                    // quarters of the e-range
#define EQ (N_E / NQ)           // 2048 codes per quarter

typedef __attribute__((ext_vector_type(8))) _Float16 half8;
typedef __attribute__((ext_vector_type(4))) float f32x4;

__device__ __forceinline__ void gl_lds16(const void* g, void* l) {
    __builtin_amdgcn_global_load_lds(
        (const __attribute__((address_space(1))) unsigned int*)g,
        (__attribute__((address_space(3))) unsigned int*)l, 16, 0, 0);
}

#define MFMA16(A_, B_, C_) __builtin_amdgcn_mfma_f32_16x16x32_f16((A_), (B_), (C_), 0, 0, 0)

// ---------------- fp32 -> fp16 (RTNE) for Z ----------------
__global__ __launch_bounds__(256) void f16_cast_kernel(const float* __restrict__ X,
                                                       ushort* __restrict__ H,
                                                       int n4) {
    int i = blockIdx.x * 256 + threadIdx.x;
    if (i >= n4) return;
    float4 v = ((const float4*)X)[i];
    float c[4] = {v.x, v.y, v.z, v.w};
    ushort hh[4];
    #pragma unroll
    for (int j = 0; j < 4; j++) {
        __half hb = __float2half(c[j]);
        hh[j] = *(ushort*)&hb;
    }
    ushort4 h = {hh[0], hh[1], hh[2], hh[3]};
    ((ushort4*)H)[i] = h;
}

// ---------------- pack W fp32 -> fp16 fragment-linear tiles (R15-proven) ----------------
// Tile (et, kt) = 1024 B; byte t*4 holds elems for lane=t>>2:
// col = lane&15, k = kt*32 + (lane>>4)*8 + (t&3)*2 (+1 in high half).
__global__ __launch_bounds__(256) void pack_w_kernel(const float* __restrict__ W,
                                                     unsigned int* __restrict__ Wt) {
    __shared__ float Ws[16 * E_DIM];
    const int et = blockIdx.x;           // 512 e-tiles of 16 codes
    const int t = threadIdx.x;
    const float4* src = (const float4*)(W + (size_t)et * 16 * E_DIM);
    #pragma unroll
    for (int i = 0; i < 8; i++)
        ((float4*)Ws)[i * 256 + t] = src[i * 256 + t];
    __syncthreads();
    const int lane = t >> 2;
    const int col = lane & 15;
    const int koff = (lane >> 4) * 8 + (t & 3) * 2;
    unsigned int* dst = Wt + (size_t)et * 16 * 256 + t;
    #pragma unroll
    for (int kt = 0; kt < 16; kt++) {
        float f0 = Ws[col * E_DIM + kt * 32 + koff];
        float f1 = Ws[col * E_DIM + kt * 32 + koff + 1];
        __half h0 = __float2half(f0), h1 = __float2half(f1);
        unsigned int u = (unsigned int)(*(ushort*)&h0) | ((unsigned int)(*(ushort*)&h1) << 16);
        dst[kt * 256] = u;
    }
}

// ---------------- wnorm[e] = sum_k W[e][k]^2 (fp32, exact) ----------------
__global__ __launch_bounds__(256) void wnorm_kernel(const float* __restrict__ W,
                                                    float* __restrict__ wnorm) {
    int wave_id = (int)((blockIdx.x * blockDim.x + threadIdx.x) >> 6);
    int lane = threadIdx.x & 63;
    if (wave_id >= N_E) return;
    const float* row = W + (size_t)wave_id * E_DIM;
    float4 v0 = *(const float4*)(row + lane * 4);
    float4 v1 = *(const float4*)(row + 256 + lane * 4);
    float s = v0.x*v0.x + v0.y*v0.y + v0.z*v0.z + v0.w*v0.w
            + v1.x*v1.x + v1.y*v1.y + v1.z*v1.z + v1.w*v1.w;
    #pragma unroll
    for (int off = 32; off; off >>= 1) s += __shfl_down(s, off);
    if (lane == 0) wnorm[wave_id] = s;
}

struct Top2 { float v0, v1; int i0, i1; };

__device__ inline Top2 merge2(Top2 A, Top2 B) {
    bool af = (A.v0 < B.v0) || (A.v0 == B.v0 && A.i0 < B.i0);
    float Wv1 = af ? A.v1 : B.v1; int Wi1 = af ? A.i1 : B.i1;
    float Lv0 = af ? B.v0 : A.v0; int Li0 = af ? B.i0 : A.i0;
    bool s2 = (Wv1 < Lv0) || (Wv1 == Lv0 && Wi1 < Li0);
    Top2 R;
    R.v0 = af ? A.v0 : B.v0; R.i0 = af ? A.i0 : B.i0;
    R.v1 = s2 ? Wv1 : Lv0;   R.i1 = s2 ? Wi1 : Li0;
    return R;
}

// ---------------- fp16 MFMA screen (K=512) + per-row top-2 per QUARTER ----------------
// FINAL (R18 revert): best verified config. Block = 4 col-groups x 2 row-groups;
// the rg pair reads IDENTICAL packed-B fragments (L1 dedup halves unique L2
// traffic); per-wave state = Areg[32] + Bbuf[8][2] + top2[8] (~2 waves/SIMD,
// the measured register envelope). No barriers in the main loop; compiler's
// counted vmcnt from static register dataflow is the only synchronization.
// R19's LDS-exchange variant regressed (sync tax > issue-path relief).
__global__ __launch_bounds__(512, 2) void argmin_mfma(
        const ushort* __restrict__ Zh, const char* __restrict__ Wt,
        const float* __restrict__ wnorm, int* __restrict__ cand) {
    __shared__ __align__(16) char Lds[65536];   // A prologue; merge aliases after

    const int t = threadIdx.x;
    const int lane = t & 63;
    const int wid = t >> 6;            // 0..7
    const int cg = wid & 3;            // col-group (16 cols)
    const int rg = wid >> 2;           // row-group (32 rows)
    const int l15 = lane & 15, l4 = lane >> 4;

    // chunked XCD remap (2048 blocks, 8 XCDs, 256-block chunks; bijective).
    const int id = blockIdx.x;
    const int orig = (id & 7) * 256 + (id >> 3);
    const int quarter = orig >> 9;     // 2 XCDs per quarter
    const int rowblk = orig & 511;
    const int row0 = rowblk * BMR;
    const int ebase = quarter * EQ;

    // ---- A prologue staging: 64 rows x 512 k, ks-major [ks][row 0..63][64B] ----
    // Swizzle on the GLOBAL side (LDS dest linear, rule #21): jj ^= (row>>1)&3.
    const int arow = (t >> 2) & 63;
    const int aswz = (t & 3) ^ ((arow >> 1) & 3);
    const ushort* Ag = Zh + (size_t)(row0 + arow) * E_DIM + ((t >> 8) & 1) * 32 + aswz * 8;
    #pragma unroll
    for (int j = 0; j < 8; j++)
        gl_lds16(Ag + j * 64, Lds + j * 8192 + t * 16);

    asm volatile("s_waitcnt vmcnt(0)" ::: "memory");
    __builtin_amdgcn_s_barrier();
    __builtin_amdgcn_sched_barrier(0);

    // ---- A fragments -> registers (wave's own 32 rows; same involution) ----
    const int kchunk_b = (l4 ^ ((l15 >> 1) & 3)) * 16;
    half8 Areg[32];                    // [ks*2 + mi], mi = 16-row group
    #pragma unroll
    for (int ks = 0; ks < 16; ks++)
        #pragma unroll
        for (int mi = 0; mi < 2; mi++)
            Areg[ks * 2 + mi] = *(const half8*)(Lds + ks * 4096
                                + (rg * 32 + mi * 16 + l15) * 64 + kchunk_b);
    asm volatile("s_waitcnt lgkmcnt(0)" ::: "memory");
    __builtin_amdgcn_sched_barrier(0);
    // no barrier: LDS untouched until the pre-merge __syncthreads()

    // ---- B: packed fragment-linear tiles; col-step s covers e-tiles s*4+cg.
    // rg=0 and rg=1 waves read IDENTICAL addresses -> L1 dedup.
    const char* Bp = Wt + ((size_t)(ebase >> 4) + cg) * 16384 + lane * 16;
    const float* wn_ptr = wnorm + ebase + cg * 16 + l15;

    // per-thread top2 over 8 row-slots q=mi*4+r; row = rg*32 + mi*16 + l4*4 + r
    float v0[8], v1[8];
    int i0[8], i1[8];
    #pragma unroll
    for (int q = 0; q < 8; q++) { v0[q] = FLT_MAX; v1[q] = FLT_MAX; i0[q] = 0; i1[q] = 0; }

    f32x4 acc[2];
    acc[0] = (f32x4){0.f, 0.f, 0.f, 0.f};
    acc[1] = (f32x4){0.f, 0.f, 0.f, 0.f};

    half8 Bbuf[8][2];   // [pair-slot][k-tile parity]; pair Q = k-tiles 2Q,2Q+1

    // prologue: pairs 0..6 of col-step 0
    #pragma unroll
    for (int p = 0; p < 7; p++) {
        Bbuf[p][0] = *(const half8*)(Bp + p * 2048);
        Bbuf[p][1] = *(const half8*)(Bp + p * 2048 + 1024);
    }

    for (int s = 0; s < 32; ++s) {      // 32 col-steps of 64 codes (4 e-tiles)
        float wn = wn_ptr[0];

        #pragma unroll
        for (int Q = 0; Q < 8; Q++) {
            __builtin_amdgcn_s_setprio(1);
            acc[0] = MFMA16(Areg[4 * Q + 0], Bbuf[Q & 7][0], acc[0]);
            acc[1] = MFMA16(Areg[4 * Q + 1], Bbuf[Q & 7][0], acc[1]);
            acc[0] = MFMA16(Areg[4 * Q + 2], Bbuf[Q & 7][1], acc[0]);
            acc[1] = MFMA16(Areg[4 * Q + 3], Bbuf[Q & 7][1], acc[1]);
            __builtin_amdgcn_s_setprio(0);
            // prefetch pair Q+7 (rolls into next col-step for Q>=1)
            if (s < 31 || Q < 1) {
                const char* src = Bp + ((Q + 7) >> 3) * 65536 + ((Q + 7) & 7) * 2048;
                Bbuf[(Q + 7) & 7][0] = *(const half8*)(src);
                Bbuf[(Q + 7) & 7][1] = *(const half8*)(src + 1024);
            }
        }

        // fold: score = wnorm[e] - 2*dot; lane's col fixed, 8 rows in acc regs
        {
            int col = ebase + (s * 4 + cg) * 16 + l15;
            #pragma unroll
            for (int mi = 0; mi < 2; mi++)
                #pragma unroll
                for (int r = 0; r < 4; r++) {
                    float sc = fmaf(-2.0f, acc[mi][r], wn);
                    int q = mi * 4 + r;
                    if (sc < v0[q])      { v1[q] = v0[q]; i1[q] = i0[q]; v0[q] = sc; i0[q] = col; }
                    else if (sc < v1[q]) { v1[q] = sc; i1[q] = col; }
                }
            acc[0] = (f32x4){0.f, 0.f, 0.f, 0.f};
            acc[1] = (f32x4){0.f, 0.f, 0.f, 0.f};
        }

        wn_ptr += 64;
        Bp += 65536;                    // 4 e-tiles * 16 k-tiles * 1KB
    }

    // ---- merge: 16-lane butterfly, then cross-cg merge via LDS ----
    __syncthreads();
    float4* SmTop = (float4*)Lds;       // [64 rows][4 col-groups]

    #pragma unroll
    for (int mi = 0; mi < 2; mi++)
        #pragma unroll
        for (int r = 0; r < 4; r++) {
            int q = mi * 4 + r;
            Top2 T = {v0[q], v1[q], i0[q], i1[q]};
            #pragma unroll
            for (int mk = 1; mk <= 8; mk <<= 1) {
                Top2 O;
                O.v0 = __shfl_xor(T.v0, mk); O.v1 = __shfl_xor(T.v1, mk);
                O.i0 = __shfl_xor(T.i0, mk); O.i1 = __shfl_xor(T.i1, mk);
                T = merge2(T, O);
            }
            if (l15 == 0) {
                int rl = rg * 32 + mi * 16 + l4 * 4 + r;
                SmTop[rl * 4 + cg] = make_float4(T.v0, __int_as_float(T.i0), T.v1, __int_as_float(T.i1));
            }
        }
    __syncthreads();
    if (t < BMR) {
        Top2 q[4];
        #pragma unroll
        for (int j = 0; j < 4; j++) {
            float4 F = SmTop[t * 4 + j];
            q[j].v0 = F.x; q[j].i0 = __float_as_int(F.y);
            q[j].v1 = F.z; q[j].i1 = __float_as_int(F.w);
        }
        Top2 T = merge2(merge2(q[0], q[1]), merge2(q[2], q[3]));
        cand[(size_t)(row0 + t) * (2 * NQ) + quarter * 2 + 0] = T.i0;
        cand[(size_t)(row0 + t) * (2 * NQ) + quarter * 2 + 1] = T.i1;
    }
}

// ---------------- fp32 rescore of 8 candidates + gather z_q + loss partial ----------------
__global__ __launch_bounds__(256) void rescore_gather_loss(
        const float* __restrict__ Z, const float* __restrict__ W,
        const float* __restrict__ wnorm, const int* __restrict__ cand,
        float* __restrict__ out, float* __restrict__ partials) {
    const int n = blockIdx.x;
    const int t = threadIdx.x;
    const int lane = t & 63, wv = t >> 6;
    int c[8];
    #pragma unroll
    for (int j = 0; j < 8; j++) c[j] = cand[(size_t)n * 8 + j];
    float2 zv = ((const float2*)(Z + (size_t)n * E_DIM))[t];
    float2 wvv[8];
    #pragma unroll
    for (int j = 0; j < 8; j++)
        wvv[j] = ((const float2*)(W + (size_t)c[j] * E_DIM))[t];
    __shared__ float red[4][8];
    #pragma unroll
    for (int j = 0; j < 8; j++) {
        float s = zv.x * wvv[j].x + zv.y * wvv[j].y;
        #pragma unroll
        for (int off = 32; off; off >>= 1) s += __shfl_down(s, off);
        if (lane == 0) red[wv][j] = s;
    }
    __syncthreads();
    float best = FLT_MAX; int bj = 0, bc = 0x7fffffff;
    #pragma unroll
    for (int j = 0; j < 8; j++) {
        float d = red[0][j] + red[1][j] + red[2][j] + red[3][j];
        float s = wnorm[c[j]] - 2.0f * d;
        if (s < best || (s == best && c[j] < bc)) { best = s; bj = j; bc = c[j]; }
    }
    float2 wq = wvv[0];                 // static-index select (rule #20)
    #pragma unroll
    for (int j = 1; j < 8; j++) if (bj == j) wq = wvv[j];
    ((float2*)(out + 1 + (size_t)n * E_DIM))[t] = wq;   // z_q_st == z_q numerically
    float d0 = wq.x - zv.x, d1 = wq.y - zv.y;
    float sl = d0 * d0 + d1 * d1;
    #pragma unroll
    for (int off = 32; off; off >>= 1) sl += __shfl_down(sl, off);
    __shared__ float red2[4];
    if (lane == 0) red2[wv] = sl;
    __syncthreads();
    if (t == 0) {
        partials[n] = red2[0] + red2[1] + red2[2] + red2[3];
        out[1 + (size_t)M_ROWS * E_DIM + n] = (float)bc;
    }
}

// ---------------- deterministic final loss reduction ----------------
__global__ __launch_bounds__(256) void loss_reduce_kernel(const float* __restrict__ partials,
                                                          float* __restrict__ out) {
    const int t = threadIdx.x;
    float s = 0.0f;
    for (int i = t; i < M_ROWS; i += 256) s += partials[i];
    #pragma unroll
    for (int off = 32; off; off >>= 1) s += __shfl_down(s, off);
    __shared__ float red[4];
    if ((t & 63) == 0) red[t >> 6] = s;
    __syncthreads();
    if (t == 0) {
        float total = red[0] + red[1] + red[2] + red[3];
        out[0] = 2.0f * total / ((float)M_ROWS * (float)E_DIM);  // beta=1 collapses
    }
}

extern "C" void kernel_launch(void* const* d_in, const int* in_sizes, int n_in,
                              void* d_out, int out_size, void* d_ws, size_t ws_size,
                              hipStream_t stream) {
    const float* Z = (const float*)d_in[0];
    const float* W = (const float*)d_in[1];
    float* out = (float*)d_out;

    char* p = (char*)d_ws;
    ushort* Zh = (ushort*)p;             p += (size_t)M_ROWS * E_DIM * 2;
    unsigned int* Wt = (unsigned int*)p; p += (size_t)N_E * E_DIM * 2;
    float* wnorm = (float*)p;            p += (size_t)N_E * 4;
    int* cand = (int*)p;                 p += (size_t)M_ROWS * 8 * 4;
    float* partials = (float*)p;         p += (size_t)M_ROWS * 4;

    f16_cast_kernel<<<(M_ROWS * E_DIM / 4 + 255) / 256, 256, 0, stream>>>(Z, Zh, M_ROWS * E_DIM / 4);
    pack_w_kernel<<<N_E / 16, 256, 0, stream>>>(W, Wt);
    wnorm_kernel<<<N_E / 4, 256, 0, stream>>>(W, wnorm);
    argmin_mfma<<<NQ * (M_ROWS / BMR), 512, 0, stream>>>(Zh, (const char*)Wt, wnorm, cand);
    rescore_gather_loss<<<M_ROWS, 256, 0, stream>>>(Z, W, wnorm, cand, out, partials);
    loss_reduce_kernel<<<1, 256, 0, stream>>>(partials, out);
}